// Round 1
// 804.389 us; speedup vs baseline: 1.0887x; 1.0887x over previous
//
#include <hip/hip_runtime.h>
#include <hip/hip_bf16.h>

// Problem constants
#define NEXP 8
#define KIN 2048
#define NOUT 2048
#define NTOK 32768

// GEMM tile (256^2, 8-phase schedule, 512 threads = 8 waves 2Mx4N)
#define BM 256
#define BN 256
#define BK 64

#define NBLK (NTOK / 256)              // 128 token blocks for rank/scatter
#define MAXTILE (NTOK / BM + NEXP - 1) // 135 worst-case M-tiles

typedef unsigned int u32;
typedef unsigned short u16;
typedef __bf16 bf16x8 __attribute__((ext_vector_type(8)));
typedef float f32x4 __attribute__((ext_vector_type(4)));

__device__ __forceinline__ u16 f2bf(float f) {
    u32 u = __float_as_uint(f);
    u += 0x7FFFu + ((u >> 16) & 1u);   // round-to-nearest-even; inputs are finite
    return (u16)(u >> 16);
}

__device__ __forceinline__ void load_lds16(const void* g, void* l) {
    __builtin_amdgcn_global_load_lds(
        (const __attribute__((address_space(1))) u32*)g,
        (__attribute__((address_space(3))) u32*)l, 16, 0, 0);
}

// Pass 1: per-block LDS histogram + per-token local rank.
__global__ void rank_k(const int* __restrict__ assign, int* __restrict__ counts,
                       int* __restrict__ rank, int* __restrict__ blockBase) {
    __shared__ int lc[NEXP];
    int t = blockIdx.x * 256 + threadIdx.x;
    if (threadIdx.x < NEXP) lc[threadIdx.x] = 0;
    __syncthreads();
    int e = assign[t];
    rank[t] = atomicAdd(&lc[e], 1);
    __syncthreads();
    if (threadIdx.x < NEXP)
        blockBase[blockIdx.x * NEXP + threadIdx.x] =
            atomicAdd(&counts[threadIdx.x], lc[threadIdx.x]);
}

// Pass 2: serial prefix + tile table. ctrl: counts[0..7], tokStart[8..16].
__global__ void prefix_k(int* __restrict__ ctrl, int4* __restrict__ tileTable) {
    if (threadIdx.x == 0) {
        int ts = 0, tile = 0;
        for (int e = 0; e < NEXP; e++) {
            ctrl[8 + e] = ts;
            int c = ctrl[e];
            int ntile = (c + BM - 1) / BM;
            for (int i = 0; i < ntile; i++)
                tileTable[tile++] = make_int4(ts + i * BM, ts + c, e, 0);
            ts += c;
        }
        ctrl[8 + NEXP] = ts;
        for (; tile < MAXTILE; tile++) tileTable[tile] = make_int4(0, 0, 0, 0);
    }
}

// Pass 3: atomic-free scatter using precomputed ranks + block bases.
__global__ void scatter_k(const int* __restrict__ assign, const int* __restrict__ ctrl,
                          const int* __restrict__ rank, const int* __restrict__ blockBase,
                          int* __restrict__ list) {
    __shared__ int base[NEXP];
    int t = blockIdx.x * 256 + threadIdx.x;
    if (threadIdx.x < NEXP)
        base[threadIdx.x] = ctrl[8 + threadIdx.x] +
                            blockBase[blockIdx.x * NEXP + threadIdx.x];
    __syncthreads();
    list[base[assign[t]] + rank[t]] = t;
}

// Streaming fp32 -> bf16 (vec8 per thread). Used for both A and W.
__global__ void conv_k(const float* __restrict__ src, u16* __restrict__ dst) {
    size_t i = ((size_t)blockIdx.x * 256 + threadIdx.x) << 3;
    const float4* s = (const float4*)(src + i);
    float4 f0 = s[0], f1 = s[1];
    uint4 o;
    o.x = (u32)f2bf(f0.x) | ((u32)f2bf(f0.y) << 16);
    o.y = (u32)f2bf(f0.z) | ((u32)f2bf(f0.w) << 16);
    o.z = (u32)f2bf(f1.x) | ((u32)f2bf(f1.y) << 16);
    o.w = (u32)f2bf(f1.z) | ((u32)f2bf(f1.w) << 16);
    *(uint4*)(dst + i) = o;
}

// ---------------------------------------------------------------------------
// 256x256x64 8-wave grouped GEMM, 4-phase/K-tile schedule with counted vmcnt.
// LDS (dynamic, 132096 B): buf b at b*65536: A [256 rows][8 slots of 16B],
// B at +32768 same shape. Swizzle: LDS[row][slot] holds global k-slot
// slot^(row&7) (involution; staged via inverse-swizzled global source,
// linear global_load_lds dest; ds_read applies the same XOR -> 2-way max).
// Double buffer = 2 K-tiles; stages lead use by 3-6 phases; vmcnt(4) once per
// K-tile (never drains to 0 in the main loop); raw s_barrier only.
// ---------------------------------------------------------------------------
#define BARS() asm volatile("s_barrier" ::: "memory")
#define WVM(N) asm volatile("s_waitcnt vmcnt(" #N ")" ::: "memory")

__global__ __launch_bounds__(512, 2) void gemm_k(const u16* __restrict__ Ab,
                                                 const u16* __restrict__ Wb,
                                                 const int* __restrict__ list,
                                                 const int4* __restrict__ tileTable,
                                                 float* __restrict__ out) {
    extern __shared__ char sh[];
    int* listLds = (int*)(sh + 131072);

    int4 tt = tileTable[blockIdx.y];
    int rowBase = tt.x, rowEnd = tt.y, e = tt.z;
    if (rowEnd <= rowBase) return;            // unused tile slot (uniform)
    int nBase = blockIdx.x * BN;
    int tid = threadIdx.x;
    int lane = tid & 63, w = tid >> 6;
    int wm = w >> 2, wn = w & 3;              // 2 x 4 wave grid

    if (tid < BM) listLds[tid] = list[min(rowBase + tid, rowEnd - 1)];
    __syncthreads();                          // full drain: vmcnt baseline = 0

    // --- staging setup: per-thread global byte offsets (32-bit for saddr) ---
    // stage row (within 128-row half) = w*16 + c*8 + (lane>>3); slot = lane&7
    // source k-slot = slot ^ (row&7) = (lane&7) ^ (lane>>3)
    int srow = (w << 4) + (lane >> 3);
    u32 ksoB = (u32)((((lane & 7) ^ (lane >> 3)) << 4));
    u32 aO00 = (u32)listLds[srow] * 4096u + ksoB;
    u32 aO01 = (u32)listLds[srow + 8] * 4096u + ksoB;
    u32 aO10 = (u32)listLds[srow + 128] * 4096u + ksoB;
    u32 aO11 = (u32)listLds[srow + 136] * 4096u + ksoB;
    u32 bO0 = (u32)(e * NOUT + nBase + srow) * 4096u + ksoB;
    u32 bO1 = bO0 + 128u * 4096u;
    u32 ldsOff = (u32)((w << 11) + (lane << 4));

#define STA(H, m, b) { char* d_ = sh + (b) * 65536 + (H) * 16384 + ldsOff;          \
        load_lds16((const char*)Ab + aO##H##0 + (m) * 128, d_);                      \
        load_lds16((const char*)Ab + aO##H##1 + (m) * 128, d_ + 1024); }
#define STB(H, m, b) { char* d_ = sh + (b) * 65536 + 32768 + (H) * 16384 + ldsOff;   \
        load_lds16((const char*)Wb + bO##H + (m) * 128, d_);                         \
        load_lds16((const char*)Wb + bO##H + 32768u + (m) * 128, d_ + 1024); }

    // --- fragment read addressing (swizzled ds_read_b128) ---
    // frag(row = base + mf*16 + (lane&15), kg = h*4 + (lane>>4));
    // slot = kg ^ (lane&7); h=1 slot = h=0 slot ^ 4 (byte ^ 0x40)
    u32 s0 = (u32)((((lane >> 4) ^ (lane & 7)) << 4));
    u32 aRow = (u32)((wm * 128 + (lane & 15)) * 128);
    u32 bRow = (u32)(32768 + (wn * 64 + (lane & 15)) * 128);

    bf16x8 ra0[4][2], ra1[4][2], rb0[2][2], rb1[2][2];
    f32x4 acc[8][4];
#pragma unroll
    for (int i = 0; i < 8; ++i)
#pragma unroll
        for (int j = 0; j < 4; ++j) acc[i][j] = (f32x4){0.f, 0.f, 0.f, 0.f};

#define RDA(dst, mf0, b) { _Pragma("unroll") for (int m_ = 0; m_ < 4; ++m_) {        \
        const char* p_ = sh + (b) * 65536 + aRow + ((mf0) + m_) * 2048;              \
        dst[m_][0] = *(const bf16x8*)(p_ + s0);                                      \
        dst[m_][1] = *(const bf16x8*)(p_ + (s0 ^ 64)); } }
#define RDB(dst, nf0, b) { _Pragma("unroll") for (int n_ = 0; n_ < 2; ++n_) {        \
        const char* p_ = sh + (b) * 65536 + bRow + ((nf0) + n_) * 2048;              \
        dst[n_][0] = *(const bf16x8*)(p_ + s0);                                      \
        dst[n_][1] = *(const bf16x8*)(p_ + (s0 ^ 64)); } }

#define QUAD(RA, RB, MO, NO) { __builtin_amdgcn_s_setprio(1);                        \
    _Pragma("unroll") for (int m_ = 0; m_ < 4; ++m_)                                 \
    _Pragma("unroll") for (int n_ = 0; n_ < 2; ++n_) {                               \
        acc[(MO)+m_][(NO)+n_] = __builtin_amdgcn_mfma_f32_16x16x32_bf16(             \
            RA[m_][0], RB[n_][0], acc[(MO)+m_][(NO)+n_], 0, 0, 0);                   \
        acc[(MO)+m_][(NO)+n_] = __builtin_amdgcn_mfma_f32_16x16x32_bf16(             \
            RA[m_][1], RB[n_][1], acc[(MO)+m_][(NO)+n_], 0, 0, 0); }                 \
    __builtin_amdgcn_s_setprio(0); }

    // --- prologue: K0 fully (8 calls) + K1 partial B0,B1,A0 (6 calls) ---
    STA(0, 0, 0); STA(1, 0, 0); STB(0, 0, 0); STB(1, 0, 0);
    STB(0, 1, 1); STB(1, 1, 1); STA(0, 1, 1);
    WVM(6);                                   // K0's 8 retired; K1's 6 in flight
    BARS();
    RDA(ra0, 0, 0); RDB(rb0, 0, 0);

    // --- main loop: K-tiles 0..29 (tail K30,K31 handled below) ---
    for (int j = 0; j < 30; ++j) {
        int b = j & 1, nb = b ^ 1;
        // q0: read RB1(j) | stage A1(j+1)->nb | Q00
        RDB(rb1, 2, b);
        STA(1, j + 1, nb);
        QUAD(ra0, rb0, 0, 0);
        BARS();
        // q1: read RA1(j) | stage B0(j+2)->b | Q01
        RDA(ra1, 4, b);
        STB(0, j + 2, b);
        QUAD(ra0, rb1, 0, 2);
        BARS();
        // q2: stage B1(j+2)->b | Q10
        STB(1, j + 2, b);
        QUAD(ra1, rb0, 4, 0);
        BARS();
        // q3: counted wait (K(j+1) staged; B0/B1(j+2) stay in flight)
        WVM(4);
        BARS();
        RDA(ra0, 0, nb);
        RDB(rb0, 0, nb);
        STA(0, j + 2, b);
        QUAD(ra1, rb1, 4, 2);
        BARS();
    }

    // --- tail: K30 (buf0) then K31 (buf1), no further staging ---
    RDB(rb1, 2, 0);
    STA(1, 31, 1);
    QUAD(ra0, rb0, 0, 0);
    BARS();
    RDA(ra1, 4, 0);
    QUAD(ra0, rb1, 0, 2);
    BARS();
    QUAD(ra1, rb0, 4, 0);
    BARS();
    WVM(0);
    BARS();
    RDA(ra0, 0, 1);
    RDB(rb0, 0, 1);
    QUAD(ra1, rb1, 4, 2);
    RDB(rb1, 2, 1);
    QUAD(ra0, rb0, 0, 0);
    RDA(ra1, 4, 1);
    QUAD(ra0, rb1, 0, 2);
    QUAD(ra1, rb0, 4, 0);
    QUAD(ra1, rb1, 4, 2);

    // --- epilogue: C/D col=lane&15, row=(lane>>4)*4+reg; scatter via listLds ---
    int cnt = rowEnd - rowBase;
    int cb = nBase + wn * 64 + (lane & 15);
#pragma unroll
    for (int mf = 0; mf < 8; ++mf) {
        int r0 = wm * 128 + mf * 16 + ((lane >> 4) << 2);
#pragma unroll
        for (int rr = 0; rr < 4; ++rr) {
            int rl = r0 + rr;
            if (rl < cnt) {
                float* orow = out + (size_t)listLds[rl] * NOUT + cb;
#pragma unroll
                for (int nf = 0; nf < 4; ++nf) orow[nf * 16] = acc[mf][nf][rr];
            }
        }
    }
#undef STA
#undef STB
#undef RDA
#undef RDB
#undef QUAD
}

// Correct-but-slow fp32 fallback if ws_size is insufficient.
__global__ void fallback_k(const float* __restrict__ A, const int* __restrict__ assign,
                           const float* __restrict__ W, float* __restrict__ out) {
    long idx = (long)blockIdx.x * 256 + threadIdx.x;  // NTOK*NOUT
    int t = (int)(idx >> 11);
    int n = (int)(idx & (NOUT - 1));
    int e = assign[t];
    const float4* a = (const float4*)(A + (size_t)t * KIN);
    const float4* w = (const float4*)(W + ((size_t)e * NOUT + n) * KIN);
    float s = 0.f;
    for (int k = 0; k < KIN / 4; k++) {
        float4 x = a[k], y = w[k];
        s += x.x * y.x + x.y * y.y + x.z * y.z + x.w * y.w;
    }
    out[idx] = s;
}

extern "C" void kernel_launch(void* const* d_in, const int* in_sizes, int n_in,
                              void* d_out, int out_size, void* d_ws, size_t ws_size,
                              hipStream_t stream) {
    const float* A = (const float*)d_in[0];
    const int* assign = (const int*)d_in[1];
    const float* W = (const float*)d_in[2];
    float* out = (float*)d_out;

    const size_t Ab_bytes = (size_t)NTOK * KIN * 2;            // 134 MB bf16 A
    const size_t Wb_bytes = (size_t)NEXP * NOUT * KIN * 2;     // 67 MB bf16 W
    const size_t list_bytes = (size_t)NTOK * 4;
    const size_t rank_bytes = (size_t)NTOK * 4;
    const size_t bb_bytes = (size_t)NBLK * NEXP * 4;
    const size_t ctrl_bytes = 256;
    const size_t tt_bytes = (size_t)MAXTILE * 16;
    const size_t need = Ab_bytes + Wb_bytes + list_bytes + rank_bytes +
                        bb_bytes + ctrl_bytes + tt_bytes;

    if (ws_size < need) {
        fallback_k<<<(NTOK * (long)NOUT) / 256, 256, 0, stream>>>(A, assign, W, out);
        return;
    }

    char* p = (char*)d_ws;
    u16* Ab = (u16*)p;                     p += Ab_bytes;
    u16* Wb = (u16*)p;                     p += Wb_bytes;
    int* list = (int*)p;                   p += list_bytes;
    int* rank = (int*)p;                   p += rank_bytes;
    int* blockBase = (int*)p;              p += bb_bytes;
    int* ctrl = (int*)p;                   p += ctrl_bytes;
    int4* tileTable = (int4*)p;

    static bool attr_done = false;
    if (!attr_done) {
        hipFuncSetAttribute((const void*)gemm_k,
                            hipFuncAttributeMaxDynamicSharedMemorySize, 132096);
        attr_done = true;
    }

    hipMemsetAsync(ctrl, 0, ctrl_bytes, stream);
    rank_k<<<NBLK, 256, 0, stream>>>(assign, ctrl, rank, blockBase);
    prefix_k<<<1, 64, 0, stream>>>(ctrl, tileTable);
    scatter_k<<<NBLK, 256, 0, stream>>>(assign, ctrl, rank, blockBase, list);
    conv_k<<<(NTOK * (KIN / 8)) / 256, 256, 0, stream>>>(A, Ab);
    conv_k<<<(NEXP * NOUT * (KIN / 8)) / 256, 256, 0, stream>>>(W, Wb);
    dim3 grid(NOUT / BN, MAXTILE);
    gemm_k<<<grid, 512, 132096, stream>>>(Ab, Wb, list, tileTable, out);
}

// Round 2
// 789.270 us; speedup vs baseline: 1.1095x; 1.0192x over previous
//
#include <hip/hip_runtime.h>
#include <hip/hip_bf16.h>

// Problem constants
#define NEXP 8
#define KIN 2048
#define NOUT 2048
#define NTOK 32768

// GEMM tile (256^2, 8-phase schedule, 512 threads = 8 waves 2Mx4N)
#define BM 256
#define BN 256
#define BK 64

#define NBLK (NTOK / 256)              // 128 token blocks for rank/scatter
#define MAXTILE (NTOK / BM + NEXP - 1) // 135 worst-case M-tiles

typedef unsigned int u32;
typedef unsigned short u16;
typedef __bf16 bf16x8 __attribute__((ext_vector_type(8)));
typedef float f32x4 __attribute__((ext_vector_type(4)));

__device__ __forceinline__ u16 f2bf(float f) {
    u32 u = __float_as_uint(f);
    u += 0x7FFFu + ((u >> 16) & 1u);   // round-to-nearest-even; inputs are finite
    return (u16)(u >> 16);
}

__device__ __forceinline__ void load_lds16(const void* g, void* l) {
    __builtin_amdgcn_global_load_lds(
        (const __attribute__((address_space(1))) u32*)g,
        (__attribute__((address_space(3))) u32*)l, 16, 0, 0);
}

// Pass 1: per-block LDS histogram + per-token local rank.
__global__ void rank_k(const int* __restrict__ assign, int* __restrict__ counts,
                       int* __restrict__ rank, int* __restrict__ blockBase) {
    __shared__ int lc[NEXP];
    int t = blockIdx.x * 256 + threadIdx.x;
    if (threadIdx.x < NEXP) lc[threadIdx.x] = 0;
    __syncthreads();
    int e = assign[t];
    rank[t] = atomicAdd(&lc[e], 1);
    __syncthreads();
    if (threadIdx.x < NEXP)
        blockBase[blockIdx.x * NEXP + threadIdx.x] =
            atomicAdd(&counts[threadIdx.x], lc[threadIdx.x]);
}

// Pass 2: prefix + tile table. ctrl: counts[0..7], tokStart[8..16].
// Serial part reduced to an 8-iter loop; tile-table writes parallel.
__global__ void prefix_k(int* __restrict__ ctrl, int4* __restrict__ tileTable) {
    __shared__ int cnt[NEXP], ts[NEXP + 1], tstart[NEXP + 1];
    int t = threadIdx.x;
    if (t < NEXP) cnt[t] = ctrl[t];
    __syncthreads();
    if (t == 0) {
        int s = 0, tile = 0;
        for (int e = 0; e < NEXP; e++) {
            ts[e] = s; tstart[e] = tile;
            s += cnt[e]; tile += (cnt[e] + BM - 1) / BM;
        }
        ts[NEXP] = s; tstart[NEXP] = tile;
        for (int e = 0; e <= NEXP; e++) ctrl[8 + e] = ts[e];
    }
    __syncthreads();
    for (int tt = t; tt < MAXTILE; tt += blockDim.x) {
        int4 v = make_int4(0, 0, 0, 0);
#pragma unroll
        for (int e = 0; e < NEXP; e++) {
            if (tt >= tstart[e] && tt < tstart[e + 1]) {
                int i = tt - tstart[e];
                v = make_int4(ts[e] + i * BM, ts[e] + cnt[e], e, 0);
            }
        }
        tileTable[tt] = v;
    }
}

// Pass 3: atomic-free scatter using precomputed ranks + block bases.
__global__ void scatter_k(const int* __restrict__ assign, const int* __restrict__ ctrl,
                          const int* __restrict__ rank, const int* __restrict__ blockBase,
                          int* __restrict__ list) {
    __shared__ int base[NEXP];
    int t = blockIdx.x * 256 + threadIdx.x;
    if (threadIdx.x < NEXP)
        base[threadIdx.x] = ctrl[8 + threadIdx.x] +
                            blockBase[blockIdx.x * NEXP + threadIdx.x];
    __syncthreads();
    list[base[assign[t]] + rank[t]] = t;
}

// Streaming fp32 -> bf16 (vec8 per thread), A and W fused into one launch.
__global__ void conv2_k(const float* __restrict__ A, u16* __restrict__ Ab,
                        const float* __restrict__ W, u16* __restrict__ Wb) {
    const size_t AV = (size_t)NTOK * KIN / 8;        // A vec8 count
    size_t v = (size_t)blockIdx.x * 256 + threadIdx.x;
    const float* src; u16* dst; size_t i;
    if (v < AV) { src = A; dst = Ab; i = v << 3; }
    else        { src = W; dst = Wb; i = (v - AV) << 3; }
    const float4* s = (const float4*)(src + i);
    float4 f0 = s[0], f1 = s[1];
    uint4 o;
    o.x = (u32)f2bf(f0.x) | ((u32)f2bf(f0.y) << 16);
    o.y = (u32)f2bf(f0.z) | ((u32)f2bf(f0.w) << 16);
    o.z = (u32)f2bf(f1.x) | ((u32)f2bf(f1.y) << 16);
    o.w = (u32)f2bf(f1.z) | ((u32)f2bf(f1.w) << 16);
    *(uint4*)(dst + i) = o;
}

// ---------------------------------------------------------------------------
// 256x256x64 8-wave grouped GEMM, 4-phase/K-tile schedule with counted vmcnt.
// LDS (dynamic, 132096 B): buf b at b*65536: A [256 rows][8 slots of 16B],
// B at +32768 same shape. Swizzle: LDS[row][slot] holds global k-slot
// slot^(row&7) (involution; staged via inverse-swizzled global source,
// linear global_load_lds dest; ds_read applies the same XOR -> 2-way max).
// Double buffer = 2 K-tiles; stages lead use by 3-6 phases; vmcnt(4) once per
// K-tile (never drains to 0 in the main loop); raw s_barrier only.
// Grid is flat 1080 blocks with m204 bijective XCD swizzle, tile-major chunks:
// XCD k owns 135 consecutive sids -> each A panel fetched by exactly one XCD,
// W panels get ~16x temporal L2 reuse per XCD.
// ---------------------------------------------------------------------------
#define BARS() asm volatile("s_barrier" ::: "memory")
#define WVM(N) asm volatile("s_waitcnt vmcnt(" #N ")" ::: "memory")

__global__ __launch_bounds__(512, 2) void gemm_k(const u16* __restrict__ Ab,
                                                 const u16* __restrict__ Wb,
                                                 const int* __restrict__ list,
                                                 const int4* __restrict__ tileTable,
                                                 float* __restrict__ out) {
    extern __shared__ char sh[];
    int* listLds = (int*)(sh + 131072);

    // XCD-aware bijective swizzle (nwg = 1080, nwg % 8 == 0)
    int orig = blockIdx.x;
    int sid = (orig & 7) * (MAXTILE) + (orig >> 3);
    int4 tt = tileTable[sid >> 3];
    int rowBase = tt.x, rowEnd = tt.y, e = tt.z;
    if (rowEnd <= rowBase) return;            // unused tile slot (uniform)
    int nBase = (sid & 7) * BN;
    int tid = threadIdx.x;
    int lane = tid & 63, w = tid >> 6;
    int wm = w >> 2, wn = w & 3;              // 2 x 4 wave grid

    if (tid < BM) listLds[tid] = list[min(rowBase + tid, rowEnd - 1)];
    __syncthreads();                          // full drain: vmcnt baseline = 0

    // --- staging setup: per-thread global byte offsets (32-bit for saddr) ---
    // stage row (within 128-row half) = w*16 + (lane>>3); slot = lane&7
    // source k-slot = slot ^ (row&7) = (lane&7) ^ (lane>>3)
    int srow = (w << 4) + (lane >> 3);
    u32 ksoB = (u32)((((lane & 7) ^ (lane >> 3)) << 4));
    u32 aO00 = (u32)listLds[srow] * 4096u + ksoB;
    u32 aO01 = (u32)listLds[srow + 8] * 4096u + ksoB;
    u32 aO10 = (u32)listLds[srow + 128] * 4096u + ksoB;
    u32 aO11 = (u32)listLds[srow + 136] * 4096u + ksoB;
    u32 bO0 = (u32)(e * NOUT + nBase + srow) * 4096u + ksoB;
    u32 bO1 = bO0 + 128u * 4096u;
    u32 ldsOff = (u32)((w << 11) + (lane << 4));

#define STA(H, m, b) { char* d_ = sh + (b) * 65536 + (H) * 16384 + ldsOff;          \
        load_lds16((const char*)Ab + aO##H##0 + (m) * 128, d_);                      \
        load_lds16((const char*)Ab + aO##H##1 + (m) * 128, d_ + 1024); }
#define STB(H, m, b) { char* d_ = sh + (b) * 65536 + 32768 + (H) * 16384 + ldsOff;   \
        load_lds16((const char*)Wb + bO##H + (m) * 128, d_);                         \
        load_lds16((const char*)Wb + bO##H + 32768u + (m) * 128, d_ + 1024); }

    // --- fragment read addressing (swizzled ds_read_b128) ---
    // frag(row = base + mf*16 + (lane&15), kg = h*4 + (lane>>4));
    // slot = kg ^ (lane&7); h=1 slot = h=0 slot ^ 4 (byte ^ 0x40)
    u32 s0 = (u32)((((lane >> 4) ^ (lane & 7)) << 4));
    u32 aRow = (u32)((wm * 128 + (lane & 15)) * 128);
    u32 bRow = (u32)(32768 + (wn * 64 + (lane & 15)) * 128);

    bf16x8 ra0[4][2], ra1[4][2], rb0[2][2], rb1[2][2];
    f32x4 acc[8][4];
#pragma unroll
    for (int i = 0; i < 8; ++i)
#pragma unroll
        for (int j = 0; j < 4; ++j) acc[i][j] = (f32x4){0.f, 0.f, 0.f, 0.f};

#define RDA(dst, mf0, b) { _Pragma("unroll") for (int m_ = 0; m_ < 4; ++m_) {        \
        const char* p_ = sh + (b) * 65536 + aRow + ((mf0) + m_) * 2048;              \
        dst[m_][0] = *(const bf16x8*)(p_ + s0);                                      \
        dst[m_][1] = *(const bf16x8*)(p_ + (s0 ^ 64)); } }
#define RDB(dst, nf0, b) { _Pragma("unroll") for (int n_ = 0; n_ < 2; ++n_) {        \
        const char* p_ = sh + (b) * 65536 + bRow + ((nf0) + n_) * 2048;              \
        dst[n_][0] = *(const bf16x8*)(p_ + s0);                                      \
        dst[n_][1] = *(const bf16x8*)(p_ + (s0 ^ 64)); } }

#define QUAD(RA, RB, MO, NO) { __builtin_amdgcn_s_setprio(1);                        \
    _Pragma("unroll") for (int m_ = 0; m_ < 4; ++m_)                                 \
    _Pragma("unroll") for (int n_ = 0; n_ < 2; ++n_) {                               \
        acc[(MO)+m_][(NO)+n_] = __builtin_amdgcn_mfma_f32_16x16x32_bf16(             \
            RA[m_][0], RB[n_][0], acc[(MO)+m_][(NO)+n_], 0, 0, 0);                   \
        acc[(MO)+m_][(NO)+n_] = __builtin_amdgcn_mfma_f32_16x16x32_bf16(             \
            RA[m_][1], RB[n_][1], acc[(MO)+m_][(NO)+n_], 0, 0, 0); }                 \
    __builtin_amdgcn_s_setprio(0); }

    // --- prologue: K0 fully (8 calls) + K1 partial B0,B1,A0 (6 calls) ---
    STA(0, 0, 0); STA(1, 0, 0); STB(0, 0, 0); STB(1, 0, 0);
    STB(0, 1, 1); STB(1, 1, 1); STA(0, 1, 1);
    WVM(6);                                   // K0's 8 retired; K1's 6 in flight
    BARS();
    RDA(ra0, 0, 0); RDB(rb0, 0, 0);

    // --- main loop: K-tiles 0..29 (tail K30,K31 handled below) ---
    for (int j = 0; j < 30; ++j) {
        int b = j & 1, nb = b ^ 1;
        // q0: read RB1(j) | stage A1(j+1)->nb | Q00
        RDB(rb1, 2, b);
        STA(1, j + 1, nb);
        QUAD(ra0, rb0, 0, 0);
        BARS();
        // q1: read RA1(j) | stage B0(j+2)->b | Q01
        RDA(ra1, 4, b);
        STB(0, j + 2, b);
        QUAD(ra0, rb1, 0, 2);
        BARS();
        // q2: stage B1(j+2)->b | Q10
        STB(1, j + 2, b);
        QUAD(ra1, rb0, 4, 0);
        BARS();
        // q3: counted wait (K(j+1) staged; B0/B1(j+2) stay in flight)
        WVM(4);
        BARS();
        RDA(ra0, 0, nb);
        RDB(rb0, 0, nb);
        STA(0, j + 2, b);
        QUAD(ra1, rb1, 4, 2);
        BARS();
    }

    // --- tail: K30 (buf0) then K31 (buf1), no further staging ---
    RDB(rb1, 2, 0);
    STA(1, 31, 1);
    QUAD(ra0, rb0, 0, 0);
    BARS();
    RDA(ra1, 4, 0);
    QUAD(ra0, rb1, 0, 2);
    BARS();
    QUAD(ra1, rb0, 4, 0);
    BARS();
    WVM(0);
    BARS();
    RDA(ra0, 0, 1);
    RDB(rb0, 0, 1);
    QUAD(ra1, rb1, 4, 2);
    RDB(rb1, 2, 1);
    QUAD(ra0, rb0, 0, 0);
    RDA(ra1, 4, 1);
    QUAD(ra0, rb1, 0, 2);
    QUAD(ra1, rb0, 4, 0);
    QUAD(ra1, rb1, 4, 2);

    // --- epilogue: C/D col=lane&15, row=(lane>>4)*4+reg; scatter via listLds ---
    int cnt = rowEnd - rowBase;
    int cb = nBase + wn * 64 + (lane & 15);
#pragma unroll
    for (int mf = 0; mf < 8; ++mf) {
        int r0 = wm * 128 + mf * 16 + ((lane >> 4) << 2);
#pragma unroll
        for (int rr = 0; rr < 4; ++rr) {
            int rl = r0 + rr;
            if (rl < cnt) {
                float* orow = out + (size_t)listLds[rl] * NOUT + cb;
#pragma unroll
                for (int nf = 0; nf < 4; ++nf) orow[nf * 16] = acc[mf][nf][rr];
            }
        }
    }
#undef STA
#undef STB
#undef RDA
#undef RDB
#undef QUAD
}

// Correct-but-slow fp32 fallback if ws_size is insufficient.
__global__ void fallback_k(const float* __restrict__ A, const int* __restrict__ assign,
                           const float* __restrict__ W, float* __restrict__ out) {
    long idx = (long)blockIdx.x * 256 + threadIdx.x;  // NTOK*NOUT
    int t = (int)(idx >> 11);
    int n = (int)(idx & (NOUT - 1));
    int e = assign[t];
    const float4* a = (const float4*)(A + (size_t)t * KIN);
    const float4* w = (const float4*)(W + ((size_t)e * NOUT + n) * KIN);
    float s = 0.f;
    for (int k = 0; k < KIN / 4; k++) {
        float4 x = a[k], y = w[k];
        s += x.x * y.x + x.y * y.y + x.z * y.z + x.w * y.w;
    }
    out[idx] = s;
}

extern "C" void kernel_launch(void* const* d_in, const int* in_sizes, int n_in,
                              void* d_out, int out_size, void* d_ws, size_t ws_size,
                              hipStream_t stream) {
    const float* A = (const float*)d_in[0];
    const int* assign = (const int*)d_in[1];
    const float* W = (const float*)d_in[2];
    float* out = (float*)d_out;

    const size_t Ab_bytes = (size_t)NTOK * KIN * 2;            // 134 MB bf16 A
    const size_t Wb_bytes = (size_t)NEXP * NOUT * KIN * 2;     // 67 MB bf16 W
    const size_t list_bytes = (size_t)NTOK * 4;
    const size_t rank_bytes = (size_t)NTOK * 4;
    const size_t bb_bytes = (size_t)NBLK * NEXP * 4;
    const size_t ctrl_bytes = 256;
    const size_t tt_bytes = (size_t)MAXTILE * 16;
    const size_t need = Ab_bytes + Wb_bytes + list_bytes + rank_bytes +
                        bb_bytes + ctrl_bytes + tt_bytes;

    if (ws_size < need) {
        fallback_k<<<(NTOK * (long)NOUT) / 256, 256, 0, stream>>>(A, assign, W, out);
        return;
    }

    char* p = (char*)d_ws;
    u16* Ab = (u16*)p;                     p += Ab_bytes;
    u16* Wb = (u16*)p;                     p += Wb_bytes;
    int* list = (int*)p;                   p += list_bytes;
    int* rank = (int*)p;                   p += rank_bytes;
    int* blockBase = (int*)p;              p += bb_bytes;
    int* ctrl = (int*)p;                   p += ctrl_bytes;
    int4* tileTable = (int4*)p;

    static bool attr_done = false;
    if (!attr_done) {
        hipFuncSetAttribute((const void*)gemm_k,
                            hipFuncAttributeMaxDynamicSharedMemorySize, 132096);
        attr_done = true;
    }

    hipMemsetAsync(ctrl, 0, ctrl_bytes, stream);
    rank_k<<<NBLK, 256, 0, stream>>>(assign, ctrl, rank, blockBase);
    prefix_k<<<1, 256, 0, stream>>>(ctrl, tileTable);
    scatter_k<<<NBLK, 256, 0, stream>>>(assign, ctrl, rank, blockBase, list);
    const int conv_blocks = (int)(((size_t)NTOK * KIN / 8 + (size_t)NEXP * NOUT * KIN / 8) / 256);
    conv2_k<<<conv_blocks, 256, 0, stream>>>(A, Ab, W, Wb);
    gemm_k<<<8 * MAXTILE, 512, 132096, stream>>>(Ab, Wb, list, tileTable, out);
}